// Round 8
// baseline (84.572 us; speedup 1.0000x reference)
//
#include <hip/hip_runtime.h>

// TemporalVoxelAttention — MFMA (bf16) fused.
// R8: TRANSPOSED GEMMs. R5-R7 showed constant ~0.32 groups/us/CU with latency
// growing linearly in resident groups -> saturated serial resource = the one
// per-CU LDS pipe (~2700 cyc/group, dominated by stC's 4x ds_write_u16 per
// lane, 4-way conflicted). Fix: compute C^T = W * X^T (swap MFMA operands;
// wfrag pack already IS the A-layout for W; ldA activation frags already ARE
// B-layout). Swapped C-frag = (col=token, 4 consecutive neurons per lane) ->
// ONE conflict-free ds_write_b64 per tile per lane. LDS [token][feat] layout
// unchanged -> attention reads unchanged. LN: in-lane sum + xor16/32 (4
// bpermutes vs 32). Biases/gamma/residual/out all become float4.
// Config: R6's 4 waves x 256 thr, 1 group/wave, fence-free, 32 KB LDS.

using bf16x8 = __attribute__((ext_vector_type(8))) __bf16;
using f32x4  = __attribute__((ext_vector_type(4))) float;

#define DEV static __device__ __forceinline__

DEV unsigned short f2bf(float f){
  union { float f; unsigned int i; } v; v.f = f;
  unsigned int x = v.i;
  x += 0x7FFFu + ((x >> 16) & 1u);           // RNE to bf16 (inputs finite)
  return (unsigned short)(x >> 16);
}

// LDS matrices: [rows][64] bf16 (128-B rows), XOR-swizzle byte ^= ((row&7)<<4).
DEV unsigned short* lp(unsigned short* base, int row, int col){
  int byte = (col << 1) ^ ((row & 7) << 4);
  return (unsigned short*)((char*)base + (row << 7) + byte);
}

// Activation fragment from [token][feat] LDS: lane holds X[t = tt*16 + (l&15)]
// [k = kt*32 + (l>>4)*8 + i]  — used as the MFMA *B* operand (n = l&15).
DEV bf16x8 ldA(const unsigned short* base, int tt, int kt, int lane){
  int row = tt*16 + (lane & 15);
  int col = kt*32 + ((lane >> 4) << 3);
  return *(const bf16x8*)lp((unsigned short*)base, row, col);
}
// Weight fragment (pre-packed): lane holds W[o = l&15][k = (l>>4)*8 + i]
// — used as the MFMA *A* operand (m = l&15).
DEV bf16x8 ldW(const unsigned short* w, int frag, int lane){
  return *(const bf16x8*)(w + (size_t)frag*512 + (size_t)lane*8);
}
// Swapped C/D: col = token = lane&15, rows = neurons mt*16 + (l>>4)*4 + r.
// Store into [token][neuron] LDS: 4 consecutive bf16 -> one b64, conflict-free.
DEV void stC(unsigned short* base, int tt, int mt, f32x4 c, int lane){
  int trow = tt*16 + (lane & 15);
  int col0 = mt*16 + ((lane >> 4) << 2);
  unsigned int lo = (unsigned int)f2bf(c[0]) | ((unsigned int)f2bf(c[1]) << 16);
  unsigned int hi = (unsigned int)f2bf(c[2]) | ((unsigned int)f2bf(c[3]) << 16);
  *(uint2*)lp(base, trow, col0) = make_uint2(lo, hi);
}
DEV f32x4 MF(bf16x8 a, bf16x8 b, f32x4 c){
  return __builtin_amdgcn_mfma_f32_16x16x32_bf16(a, b, c, 0, 0, 0);
}
DEV f32x4 bias4(const float* p){
  float4 b = *(const float4*)p;
  return (f32x4){b.x, b.y, b.z, b.w};
}

DEV void ld16(const unsigned short* base, int row, int col0, float* o){
  uint4 a = *(const uint4*)lp((unsigned short*)base, row, col0);
  uint4 b = *(const uint4*)lp((unsigned short*)base, row, col0 + 8);
  unsigned int w[8] = {a.x, a.y, a.z, a.w, b.x, b.y, b.z, b.w};
  #pragma unroll
  for (int i = 0; i < 8; ++i){
    union { unsigned int u; float f; } lo, hi;
    lo.u = w[i] << 16; hi.u = w[i] & 0xFFFF0000u;
    o[2*i] = lo.f; o[2*i+1] = hi.f;
  }
}
DEV void st16(unsigned short* base, int row, int col0, const float* f){
  unsigned int w[8];
  #pragma unroll
  for (int i = 0; i < 8; ++i)
    w[i] = (unsigned int)f2bf(f[2*i]) | ((unsigned int)f2bf(f[2*i+1]) << 16);
  *(uint4*)lp(base, row, col0)     = make_uint4(w[0], w[1], w[2], w[3]);
  *(uint4*)lp(base, row, col0 + 8) = make_uint4(w[4], w[5], w[6], w[7]);
}

DEV bf16x8 pack8(const float* f){
  union { bf16x8 v; unsigned short u[8]; } r;
  #pragma unroll
  for (int i = 0; i < 8; ++i) r.u[i] = f2bf(f[i]);
  return r.v;
}

// Swapped LayerNorm: x[nt][r] = value(token = lane&15, neuron = nt*16+r0+r).
// Per-token sum = in-lane 16 values + xor16 + xor32 (lanes t,t+16,t+32,t+48).
DEV void layer_norm_sw(f32x4 x[4], const float* g, const float* b, int lane){
  float s = 0.f, s2 = 0.f;
  #pragma unroll
  for (int nt = 0; nt < 4; ++nt)
    #pragma unroll
    for (int r = 0; r < 4; ++r){ s += x[nt][r]; s2 += x[nt][r]*x[nt][r]; }
  s  += __shfl_xor(s, 16);  s2 += __shfl_xor(s2, 16);
  s  += __shfl_xor(s, 32);  s2 += __shfl_xor(s2, 32);
  float mu = s * (1.f/64.f);
  float rs = rsqrtf(s2 * (1.f/64.f) - mu*mu + 1e-5f);
  const int r0 = (lane >> 4) << 2;
  #pragma unroll
  for (int nt = 0; nt < 4; ++nt){
    float4 gg = *(const float4*)&g[nt*16 + r0];
    float4 bb = *(const float4*)&b[nt*16 + r0];
    x[nt][0] = (x[nt][0] - mu) * rs * gg.x + bb.x;
    x[nt][1] = (x[nt][1] - mu) * rs * gg.y + bb.y;
    x[nt][2] = (x[nt][2] - mu) * rs * gg.z + bb.z;
    x[nt][3] = (x[nt][3] - mu) * rs * gg.w + bb.w;
  }
}

// ---------------- weight packing (unchanged layout; now used as A-frags) ----
// 0: pp_w1 (K=8 pad 32, N=64)   base 0,  4 frags
// 1: pp_w2 (K=64,  N=64)        base 4,  8
// 2: in_proj (K=64, N=192)      base 12, 24
// 3: out_w (K=64, N=64)         base 36, 8
// 4: ffn_w1 (K=64, N=128)       base 44, 16
// 5: ffn_w2 (K=128, N=64)       base 60, 16
// 6: op_w1 (K=64, N=64)         base 76, 8
// 7: op_w2 (K=64, N=64)         base 84, 8   -> 92 frags total
__global__ void tva_pack_weights(const float* __restrict__ pp_w1, const float* __restrict__ pp_w2,
                                 const float* __restrict__ in_proj_w, const float* __restrict__ out_w,
                                 const float* __restrict__ ffn_w1, const float* __restrict__ ffn_w2,
                                 const float* __restrict__ op_w1, const float* __restrict__ op_w2,
                                 unsigned short* __restrict__ ws)
{
  int b = blockIdx.x, lane = threadIdx.x;
  const float* W; int base, ktiles, K;
  if      (b < 4)  { W = pp_w1;     base = 0;  ktiles = 1; K = 8;   }
  else if (b < 12) { W = pp_w2;     base = 4;  ktiles = 2; K = 64;  }
  else if (b < 36) { W = in_proj_w; base = 12; ktiles = 2; K = 64;  }
  else if (b < 44) { W = out_w;     base = 36; ktiles = 2; K = 64;  }
  else if (b < 60) { W = ffn_w1;    base = 44; ktiles = 2; K = 64;  }
  else if (b < 76) { W = ffn_w2;    base = 60; ktiles = 4; K = 128; }
  else if (b < 84) { W = op_w1;     base = 76; ktiles = 2; K = 64;  }
  else             { W = op_w2;     base = 84; ktiles = 2; K = 64;  }
  int local = b - base;
  int nt = local / ktiles, kt = local % ktiles;
  int n  = nt*16 + (lane & 15);
  int k0 = kt*32 + ((lane >> 4) << 3);
  unsigned short* dst = ws + (size_t)b*512 + (size_t)lane*8;
  #pragma unroll
  for (int i = 0; i < 8; ++i){
    int k = k0 + i;
    float v = (k < K) ? W[(size_t)n*K + k] : 0.0f;
    dst[i] = f2bf(v);
  }
}

// ---------------- main kernel ----------------
__global__ __launch_bounds__(256)
void tva_main(const float* __restrict__ vf, const float* __restrict__ vox,
              const int* __restrict__ num_points,
              const float* __restrict__ pp_b1, const float* __restrict__ pp_b2,
              const float* __restrict__ ipb,  const float* __restrict__ outb,
              const float* __restrict__ ln1g, const float* __restrict__ ln1b,
              const float* __restrict__ f1b,  const float* __restrict__ f2bv,
              const float* __restrict__ ln2g, const float* __restrict__ ln2b,
              const float* __restrict__ o1b,  const float* __restrict__ o2b,
              const unsigned short* __restrict__ wfrag,
              float* __restrict__ out, int nvox)
{
  __shared__ unsigned short smem[4 * 64 * 64];   // 32 KB: 4 waves x 8 KB
  const int tid  = threadIdx.x;
  const int wv   = tid >> 6;
  const int lane = tid & 63;
  unsigned short* X = smem + wv * (64*64);  // rows 0..47: hidden -> tok12 -> K -> V -> ffn-h -> op1-h
  unsigned short* Q = X + 48*64;            // rows 0..15: q -> ctx -> postLN1 -> postLN2

  const int v0 = (blockIdx.x * 4 + wv) * 16;
  if (v0 >= nvox) return;                   // tail waves (no barriers -> safe)
  const int cl = lane & 15;
  const int r0 = (lane >> 4) << 2;

  // ======== Phase A: point aggregation (4 lanes per voxel) ========
  const int vi = lane >> 2, pq = lane & 3;
  const int np = num_points[v0 + vi];
  float cs[8] = {0,0,0,0,0,0,0,0}, hs[8] = {0,0,0,0,0,0,0,0};
  float cc = 0.f, hc = 0.f;
  const float4* vp = (const float4*)(vox + (size_t)(v0 + vi) * 384);
  #pragma unroll
  for (int k = 0; k < 12; ++k){
    int p = pq + (k << 2);
    float4 a = vp[p*2], b = vp[p*2 + 1];
    float pm = (p < np) ? 1.f : 0.f;
    float cm = (b.w > 0.5f) ? pm : 0.f;   // current: flag>0.5 & in-range
    float hm = pm - cm;                   // history: in-range & !current
    cc += cm; hc += hm;
    cs[0] += a.x*cm; cs[1] += a.y*cm; cs[2] += a.z*cm; cs[3] += a.w*cm;
    cs[4] += b.x*cm; cs[5] += b.y*cm; cs[6] += b.z*cm; cs[7] += b.w*cm;
    hs[0] += a.x*hm; hs[1] += a.y*hm; hs[2] += a.z*hm; hs[3] += a.w*hm;
    hs[4] += b.x*hm; hs[5] += b.y*hm; hs[6] += b.z*hm; hs[7] += b.w*hm;
  }
  #pragma unroll
  for (int o = 1; o <= 2; o <<= 1){
    cc += __shfl_xor(cc, o); hc += __shfl_xor(hc, o);
    #pragma unroll
    for (int j = 0; j < 8; ++j){
      cs[j] += __shfl_xor(cs[j], o);
      hs[j] += __shfl_xor(hs[j], o);
    }
  }
  const float icc = 1.f / fmaxf(cc, 1.f);
  const float ihc = 1.f / fmaxf(hc, 1.f);
  const unsigned int myfw = (cc > 0.f ? 1u : 0u) | (hc > 0.f ? 2u : 0u);

  // Build pp-GEMM1 activation B-frags in-register (16 shuffles).
  // B-frag: lane holds X[t = l&15][k = (l>>4)*8 + i]; k>=8 zero-padded.
  bf16x8 ac, ah;
  {
    const int src = cl * 4;   // any lane of voxel (lane&15) has the full sums
    float cf[8], hf[8];
    #pragma unroll
    for (int i = 0; i < 8; ++i){
      cf[i] = __shfl(cs[i]*icc, src);
      hf[i] = __shfl(hs[i]*ihc, src);
    }
    union { bf16x8 v; unsigned short u[8]; } rc, rh;
    #pragma unroll
    for (int i = 0; i < 8; ++i){
      rc.u[i] = (lane < 16) ? f2bf(cf[i]) : (unsigned short)0;
      rh.u[i] = (lane < 16) ? f2bf(hf[i]) : (unsigned short)0;
    }
    ac = rc.v; ah = rh.v;
  }

  // ======== Phase B: point_proj (8->64 relu, 64->64) ========
  #pragma unroll
  for (int nt = 0; nt < 4; ++nt){
    f32x4 binit = bias4(&pp_b1[nt*16 + r0]);
    bf16x8 W = ldW(wfrag, nt, lane);
    f32x4 c0 = MF(W, ac, binit);
    f32x4 c1 = MF(W, ah, binit);
    #pragma unroll
    for (int r = 0; r < 4; ++r){ c0[r] = fmaxf(c0[r], 0.f); c1[r] = fmaxf(c1[r], 0.f); }
    stC(X, 0, nt, c0, lane);   // hidden(cur) rows 0..15
    stC(X, 1, nt, c1, lane);   // hidden(his) rows 16..31
  }
  {
    bf16x8 hfr[2][2];
    #pragma unroll
    for (int m = 0; m < 2; ++m)
      #pragma unroll
      for (int kt = 0; kt < 2; ++kt) hfr[m][kt] = ldA(X, m, kt, lane);
    // reads precede overwriting stores in program order (per-wave LDS order).
    #pragma unroll
    for (int nt = 0; nt < 4; ++nt){
      f32x4 binit = bias4(&pp_b2[nt*16 + r0]);
      bf16x8 W0 = ldW(wfrag, 4 + nt*2 + 0, lane);
      bf16x8 W1 = ldW(wfrag, 4 + nt*2 + 1, lane);
      #pragma unroll
      for (int m = 0; m < 2; ++m){
        f32x4 c = MF(W0, hfr[m][0], binit);
        c = MF(W1, hfr[m][1], c);
        stC(X, m, nt, c, lane);   // token1 rows 0..15, token2 rows 16..31
      }
    }
  }

  // ======== Phase C: QKV projections ========
  bf16x8 at[3][2];
  {
    // token0 B-frags straight from global vf (f32 -> bf16)
    const float* s = vf + (size_t)(v0 + cl) * 64 + ((lane >> 4) << 3);
    #pragma unroll
    for (int kt = 0; kt < 2; ++kt){
      float4 x0 = *(const float4*)(s + kt*32);
      float4 x1 = *(const float4*)(s + kt*32 + 4);
      float f[8] = {x0.x, x0.y, x0.z, x0.w, x1.x, x1.y, x1.z, x1.w};
      at[0][kt] = pack8(f);
    }
    #pragma unroll
    for (int kt = 0; kt < 2; ++kt){
      at[1][kt] = ldA(X, 0, kt, lane);
      at[2][kt] = ldA(X, 1, kt, lane);
    }
  }
  // q (token0 only), pre-scaled by 1/sqrt(DH)=0.25 -> Q  ([voxel][qdim])
  #pragma unroll
  for (int nt = 0; nt < 4; ++nt){
    f32x4 c = bias4(&ipb[nt*16 + r0]);
    c = MF(ldW(wfrag, 12 + nt*2 + 0, lane), at[0][0], c);
    c = MF(ldW(wfrag, 12 + nt*2 + 1, lane), at[0][1], c);
    #pragma unroll
    for (int r = 0; r < 4; ++r) c[r] *= 0.25f;
    stC(Q, 0, nt, c, lane);
  }
  // K (3 tokens) -> X rows 0..47  ([token-row][kdim])
  #pragma unroll
  for (int nt = 0; nt < 4; ++nt){
    int ntg = 4 + nt;
    f32x4 binit = bias4(&ipb[64 + nt*16 + r0]);
    bf16x8 W0 = ldW(wfrag, 12 + ntg*2 + 0, lane);
    bf16x8 W1 = ldW(wfrag, 12 + ntg*2 + 1, lane);
    #pragma unroll
    for (int m = 0; m < 3; ++m){
      f32x4 c = MF(W0, at[m][0], binit);
      c = MF(W1, at[m][1], c);
      stC(X, m, nt, c, lane);
    }
  }

  // ======== Phase D1: scores + softmax (lane = (voxel, head)) ========
  const int av = cl, hh2 = lane >> 4;
  float p0, p1, p2;
  {
    unsigned int fw = (unsigned int)__shfl((int)myfw, av*4);
    bool caZ = (fw & 1u) != 0, hpZ = (fw & 2u) != 0;
    float q[16]; ld16(Q, av, hh2*16, q);
    float sc[3];
    #pragma unroll
    for (int m = 0; m < 3; ++m){
      float kv[16]; ld16(X, m*16 + av, hh2*16, kv);
      float d = 0.f;
      #pragma unroll
      for (int j = 0; j < 16; ++j) d += q[j]*kv[j];
      sc[m] = d;
    }
    float mx = sc[0];
    mx = caZ ? fmaxf(mx, sc[1]) : mx;
    mx = hpZ ? fmaxf(mx, sc[2]) : mx;
    float e0 = __expf(sc[0] - mx);
    float e1 = caZ ? __expf(sc[1] - mx) : 0.f;
    float e2 = hpZ ? __expf(sc[2] - mx) : 0.f;
    float inv = 1.f / (e0 + e1 + e2);
    p0 = e0*inv; p1 = e1*inv; p2 = e2*inv;
  }

  // ======== Phase C2: V projection -> X (K reads precede in program order) ====
  #pragma unroll
  for (int nt = 0; nt < 4; ++nt){
    int ntg = 8 + nt;
    f32x4 binit = bias4(&ipb[128 + nt*16 + r0]);
    bf16x8 W0 = ldW(wfrag, 12 + ntg*2 + 0, lane);
    bf16x8 W1 = ldW(wfrag, 12 + ntg*2 + 1, lane);
    #pragma unroll
    for (int m = 0; m < 3; ++m){
      f32x4 c = MF(W0, at[m][0], binit);
      c = MF(W1, at[m][1], c);
      stC(X, m, nt, c, lane);
    }
  }

  // ======== Phase D2: ctx = p . V  -> Q (overwrites q) ========
  {
    float ctx[16];
    float vv[16];
    ld16(X, av, hh2*16, vv);
    #pragma unroll
    for (int j = 0; j < 16; ++j) ctx[j] = p0*vv[j];
    ld16(X, 16 + av, hh2*16, vv);
    #pragma unroll
    for (int j = 0; j < 16; ++j) ctx[j] += p1*vv[j];
    ld16(X, 32 + av, hh2*16, vv);
    #pragma unroll
    for (int j = 0; j < 16; ++j) ctx[j] += p2*vv[j];
    st16(Q, av, hh2*16, ctx);
  }

  // ======== Phase E: attn_out + residual + LN1 (token0 only) ========
  f32x4 res1[4];
  {
    bf16x8 a0 = ldA(Q, 0, 0, lane), a1 = ldA(Q, 0, 1, lane);
    #pragma unroll
    for (int nt = 0; nt < 4; ++nt){
      f32x4 c = bias4(&outb[nt*16 + r0]);
      c = MF(ldW(wfrag, 36 + nt*2 + 0, lane), a0, c);
      c = MF(ldW(wfrag, 36 + nt*2 + 1, lane), a1, c);
      float4 rv = *(const float4*)&vf[(size_t)(v0 + cl)*64 + nt*16 + r0];
      c[0] += rv.x; c[1] += rv.y; c[2] += rv.z; c[3] += rv.w;
      res1[nt] = c;
    }
    layer_norm_sw(res1, ln1g, ln1b, lane);
    #pragma unroll
    for (int nt = 0; nt < 4; ++nt) stC(Q, 0, nt, res1[nt], lane);
  }

  // ======== Phase F: FFN (64->128 relu ->64) + residual + LN2 ========
  f32x4 tk2[4];
  {
    bf16x8 a0 = ldA(Q, 0, 0, lane), a1 = ldA(Q, 0, 1, lane);
    #pragma unroll
    for (int nt = 0; nt < 4; ++nt) tk2[nt] = bias4(&f2bv[nt*16 + r0]);
    // h cols 0..63
    #pragma unroll
    for (int nt = 0; nt < 4; ++nt){
      f32x4 c = bias4(&f1b[nt*16 + r0]);
      c = MF(ldW(wfrag, 44 + nt*2 + 0, lane), a0, c);
      c = MF(ldW(wfrag, 44 + nt*2 + 1, lane), a1, c);
      #pragma unroll
      for (int r = 0; r < 4; ++r) c[r] = fmaxf(c[r], 0.f);
      stC(X, 0, nt, c, lane);
    }
    {
      bf16x8 h0 = ldA(X, 0, 0, lane), h1 = ldA(X, 0, 1, lane);
      #pragma unroll
      for (int nt = 0; nt < 4; ++nt){
        tk2[nt] = MF(ldW(wfrag, 60 + nt*4 + 0, lane), h0, tk2[nt]);
        tk2[nt] = MF(ldW(wfrag, 60 + nt*4 + 1, lane), h1, tk2[nt]);
      }
    }
    // h cols 64..127 (h reads precede these stores in program order)
    #pragma unroll
    for (int nt = 4; nt < 8; ++nt){
      f32x4 c = bias4(&f1b[nt*16 + r0]);
      c = MF(ldW(wfrag, 44 + nt*2 + 0, lane), a0, c);
      c = MF(ldW(wfrag, 44 + nt*2 + 1, lane), a1, c);
      #pragma unroll
      for (int r = 0; r < 4; ++r) c[r] = fmaxf(c[r], 0.f);
      stC(X, 0, nt - 4, c, lane);
    }
    {
      bf16x8 h0 = ldA(X, 0, 0, lane), h1 = ldA(X, 0, 1, lane);
      #pragma unroll
      for (int nt = 0; nt < 4; ++nt){
        tk2[nt] = MF(ldW(wfrag, 60 + nt*4 + 2, lane), h0, tk2[nt]);
        tk2[nt] = MF(ldW(wfrag, 60 + nt*4 + 3, lane), h1, tk2[nt]);
      }
    }
    #pragma unroll
    for (int nt = 0; nt < 4; ++nt)
      #pragma unroll
      for (int r = 0; r < 4; ++r) tk2[nt][r] += res1[nt][r];
    layer_norm_sw(tk2, ln2g, ln2b, lane);
    #pragma unroll
    for (int nt = 0; nt < 4; ++nt) stC(Q, 0, nt, tk2[nt], lane);
  }

  // ======== Phase G: output MLP + gate + final residual ========
  {
    bf16x8 a0 = ldA(Q, 0, 0, lane), a1 = ldA(Q, 0, 1, lane);
    #pragma unroll
    for (int nt = 0; nt < 4; ++nt){
      f32x4 c = bias4(&o1b[nt*16 + r0]);
      c = MF(ldW(wfrag, 76 + nt*2 + 0, lane), a0, c);
      c = MF(ldW(wfrag, 76 + nt*2 + 1, lane), a1, c);
      #pragma unroll
      for (int r = 0; r < 4; ++r) c[r] = fmaxf(c[r], 0.f);
      stC(X, 0, nt, c, lane);
    }
    bf16x8 b0 = ldA(X, 0, 0, lane), b1 = ldA(X, 0, 1, lane);
    unsigned int fw2 = (unsigned int)__shfl((int)myfw, cl*4);
    float keep = (fw2 & 2u) ? 1.f : 0.f;       // history_present gate (per voxel)
    #pragma unroll
    for (int nt = 0; nt < 4; ++nt){
      f32x4 c = bias4(&o2b[nt*16 + r0]);
      c = MF(ldW(wfrag, 84 + nt*2 + 0, lane), b0, c);
      c = MF(ldW(wfrag, 84 + nt*2 + 1, lane), b1, c);
      size_t idx = (size_t)(v0 + cl)*64 + nt*16 + r0;
      float4 rv = *(const float4*)&vf[idx];
      float4 o;
      o.x = rv.x + keep * c[0];
      o.y = rv.y + keep * c[1];
      o.z = rv.z + keep * c[2];
      o.w = rv.w + keep * c[3];
      *(float4*)&out[idx] = o;
    }
  }
}

extern "C" void kernel_launch(void* const* d_in, const int* in_sizes, int n_in,
                              void* d_out, int out_size, void* d_ws, size_t ws_size,
                              hipStream_t stream)
{
  (void)n_in; (void)out_size; (void)ws_size;
  const float* vf    = (const float*)d_in[0];
  const float* vox   = (const float*)d_in[1];
  const float* pp_w1 = (const float*)d_in[2];
  const float* pp_b1 = (const float*)d_in[3];
  const float* pp_w2 = (const float*)d_in[4];
  const float* pp_b2 = (const float*)d_in[5];
  const float* ipw   = (const float*)d_in[6];
  const float* ipb   = (const float*)d_in[7];
  const float* outw  = (const float*)d_in[8];
  const float* outb  = (const float*)d_in[9];
  const float* ln1g  = (const float*)d_in[10];
  const float* ln1b  = (const float*)d_in[11];
  const float* f1w   = (const float*)d_in[12];
  const float* f1b   = (const float*)d_in[13];
  const float* f2w   = (const float*)d_in[14];
  const float* f2b   = (const float*)d_in[15];
  const float* ln2g  = (const float*)d_in[16];
  const float* ln2b  = (const float*)d_in[17];
  const float* o1w   = (const float*)d_in[18];
  const float* o1b   = (const float*)d_in[19];
  const float* o2w   = (const float*)d_in[20];
  const float* o2b   = (const float*)d_in[21];
  const int*   npts  = (const int*)d_in[22];
  unsigned short* wfrag = (unsigned short*)d_ws;   // 92*512*2 = 94208 B
  float* out = (float*)d_out;

  const int nvox = in_sizes[0] / 64;       // 100000
  const int ngrp = nvox / 16;              // 6250 wave-groups
  const int nblk = (ngrp + 3) / 4;         // 1563 blocks x 4 waves
  tva_pack_weights<<<92, 64, 0, stream>>>(pp_w1, pp_w2, ipw, outw, f1w, f2w, o1w, o2w, wfrag);
  tva_main<<<nblk, 256, 0, stream>>>(vf, vox, npts, pp_b1, pp_b2, ipb, outb,
                                     ln1g, ln1b, f1b, f2b, ln2g, ln2b, o1b, o2b,
                                     wfrag, out, nvox);
}

// Round 9
// 81.184 us; speedup vs baseline: 1.0417x; 1.0417x over previous
//
#include <hip/hip_runtime.h>

// TemporalVoxelAttention — MFMA (bf16), split into two kernels.
// R9: (1) tva_aggregate: streaming masked-mean kernel, lane-contiguous 16B
// reads (minimal line requests), writes bf16 means (32B/voxel) + flags to
// d_ws. Pure BW kernel -> individually roofline-able. (2) tva_main: R6 body
// (R8 transposition reverted: it 4x'd bank conflicts) with the aggregation
// phase replaced by two 16-lane bf16x8 mean loads + per-lane flag loads.
// Rationale: R5-R8 showed throughput pinned at ~0.32 groups/us/CU invariant
// to waves (R6), weight reuse (R7), LDS writes (R8) — the untouched per-group
// terms are the fused aggregation stream + transformer body size. Splitting
// shrinks per-group cost ~40% and makes each kernel's counters attributable.
// d_ws: [0,94208) wfrag | [94208, +3.2MB) means bf16[voxel][16] | flags int.

using bf16x8 = __attribute__((ext_vector_type(8))) __bf16;
using f32x4  = __attribute__((ext_vector_type(4))) float;

#define DEV static __device__ __forceinline__

DEV unsigned short f2bf(float f){
  union { float f; unsigned int i; } v; v.f = f;
  unsigned int x = v.i;
  x += 0x7FFFu + ((x >> 16) & 1u);           // RNE to bf16 (inputs finite)
  return (unsigned short)(x >> 16);
}

// LDS matrices: [rows][64] bf16 (128-B rows), XOR-swizzle byte ^= ((row&7)<<4).
DEV unsigned short* lp(unsigned short* base, int row, int col){
  int byte = (col << 1) ^ ((row & 7) << 4);
  return (unsigned short*)((char*)base + (row << 7) + byte);
}

// A-fragment: lane holds A[row = mt*16 + (lane&15)][k = kt*32 + (lane>>4)*8 + i]
DEV bf16x8 ldA(const unsigned short* base, int mt, int kt, int lane){
  int row = mt*16 + (lane & 15);
  int col = kt*32 + ((lane >> 4) << 3);
  return *(const bf16x8*)lp((unsigned short*)base, row, col);
}
// B-fragment: pre-packed in ws, lane-contiguous 16B
DEV bf16x8 ldB(const unsigned short* w, int frag, int lane){
  return *(const bf16x8*)(w + (size_t)frag*512 + (size_t)lane*8);
}
// C/D: col = lane&15, row = mt*16 + (lane>>4)*4 + r
DEV void stC(unsigned short* base, int mt, int nt, f32x4 c, int lane){
  int col  = nt*16 + (lane & 15);
  int row0 = mt*16 + ((lane >> 4) << 2);
  #pragma unroll
  for (int r = 0; r < 4; ++r) *lp(base, row0 + r, col) = f2bf(c[r]);
}
DEV f32x4 MF(bf16x8 a, bf16x8 b, f32x4 c){
  return __builtin_amdgcn_mfma_f32_16x16x32_bf16(a, b, c, 0, 0, 0);
}

DEV void ld16(const unsigned short* base, int row, int col0, float* o){
  uint4 a = *(const uint4*)lp((unsigned short*)base, row, col0);
  uint4 b = *(const uint4*)lp((unsigned short*)base, row, col0 + 8);
  unsigned int w[8] = {a.x, a.y, a.z, a.w, b.x, b.y, b.z, b.w};
  #pragma unroll
  for (int i = 0; i < 8; ++i){
    union { unsigned int u; float f; } lo, hi;
    lo.u = w[i] << 16; hi.u = w[i] & 0xFFFF0000u;
    o[2*i] = lo.f; o[2*i+1] = hi.f;
  }
}
DEV void st16(unsigned short* base, int row, int col0, const float* f){
  unsigned int w[8];
  #pragma unroll
  for (int i = 0; i < 8; ++i)
    w[i] = (unsigned int)f2bf(f[2*i]) | ((unsigned int)f2bf(f[2*i+1]) << 16);
  *(uint4*)lp(base, row, col0)     = make_uint4(w[0], w[1], w[2], w[3]);
  *(uint4*)lp(base, row, col0 + 8) = make_uint4(w[4], w[5], w[6], w[7]);
}

DEV bf16x8 pack8(const float* f){
  union { bf16x8 v; unsigned short u[8]; } r;
  #pragma unroll
  for (int i = 0; i < 8; ++i) r.u[i] = f2bf(f[i]);
  return r.v;
}

// LayerNorm over 64 cols for one 16-row M-tile held as 4 C-frags.
DEV void layer_norm16(f32x4 x[4], const float* g, const float* b, int lane){
  float s[4], s2[4];
  #pragma unroll
  for (int r = 0; r < 4; ++r){
    s[r]  = x[0][r] + x[1][r] + x[2][r] + x[3][r];
    s2[r] = x[0][r]*x[0][r] + x[1][r]*x[1][r] + x[2][r]*x[2][r] + x[3][r]*x[3][r];
  }
  #pragma unroll
  for (int o = 1; o <= 8; o <<= 1){
    #pragma unroll
    for (int r = 0; r < 4; ++r){
      s[r]  += __shfl_xor(s[r],  o);
      s2[r] += __shfl_xor(s2[r], o);
    }
  }
  float mu[4], rs[4];
  #pragma unroll
  for (int r = 0; r < 4; ++r){
    mu[r] = s[r] * (1.f/64.f);
    float var = s2[r] * (1.f/64.f) - mu[r]*mu[r];
    rs[r] = rsqrtf(var + 1e-5f);
  }
  const int cl = lane & 15;
  #pragma unroll
  for (int nt = 0; nt < 4; ++nt){
    float gg = g[nt*16 + cl], bb = b[nt*16 + cl];
    #pragma unroll
    for (int r = 0; r < 4; ++r)
      x[nt][r] = (x[nt][r] - mu[r]) * rs[r] * gg + bb;
  }
}

// ---------------- weight packing (unchanged) ----------------
__global__ void tva_pack_weights(const float* __restrict__ pp_w1, const float* __restrict__ pp_w2,
                                 const float* __restrict__ in_proj_w, const float* __restrict__ out_w,
                                 const float* __restrict__ ffn_w1, const float* __restrict__ ffn_w2,
                                 const float* __restrict__ op_w1, const float* __restrict__ op_w2,
                                 unsigned short* __restrict__ ws)
{
  int b = blockIdx.x, lane = threadIdx.x;
  const float* W; int base, ktiles, K;
  if      (b < 4)  { W = pp_w1;     base = 0;  ktiles = 1; K = 8;   }
  else if (b < 12) { W = pp_w2;     base = 4;  ktiles = 2; K = 64;  }
  else if (b < 36) { W = in_proj_w; base = 12; ktiles = 2; K = 64;  }
  else if (b < 44) { W = out_w;     base = 36; ktiles = 2; K = 64;  }
  else if (b < 60) { W = ffn_w1;    base = 44; ktiles = 2; K = 64;  }
  else if (b < 76) { W = ffn_w2;    base = 60; ktiles = 4; K = 128; }
  else if (b < 84) { W = op_w1;     base = 76; ktiles = 2; K = 64;  }
  else             { W = op_w2;     base = 84; ktiles = 2; K = 64;  }
  int local = b - base;
  int nt = local / ktiles, kt = local % ktiles;
  int n  = nt*16 + (lane & 15);
  int k0 = kt*32 + ((lane >> 4) << 3);
  unsigned short* dst = ws + (size_t)b*512 + (size_t)lane*8;
  #pragma unroll
  for (int i = 0; i < 8; ++i){
    int k = k0 + i;
    float v = (k < K) ? W[(size_t)n*K + k] : 0.0f;
    dst[i] = f2bf(v);
  }
}

// ---------------- aggregation kernel (streaming, line-coalesced) ----------
// 8 lanes/voxel; lane j reads float4 index (j + 8k) of its voxel: consecutive
// lanes -> consecutive 16B -> each wave instruction touches the minimum line
// count. Pair (even,odd) lanes hold (ch0-3, ch4-7) of the same point; flag
// (ch7) shared via shfl_xor(1). Parity-preserving xor2/xor4 reduce.
__global__ __launch_bounds__(256)
void tva_aggregate(const float* __restrict__ vox, const int* __restrict__ num_points,
                   unsigned short* __restrict__ means, int* __restrict__ flags, int nvox)
{
  const int tid  = threadIdx.x;
  const int wv   = tid >> 6, lane = tid & 63;
  const int j    = lane & 7;
  const int v    = (blockIdx.x*4 + wv)*8 + (lane >> 3);
  if (v >= nvox) return;
  const int np = num_points[v];
  const float4* base = (const float4*)(vox + (size_t)v*384);
  float s[4] = {0,0,0,0}, h[4] = {0,0,0,0};
  float cc = 0.f, hc = 0.f;
  #pragma unroll
  for (int k = 0; k < 12; ++k){
    float4 x = base[j + 8*k];
    int p = 4*k + (j >> 1);
    float fl = __shfl_xor(x.w, 1);         // even lane gets odd's ch7
    fl = (j & 1) ? x.w : fl;               // odd lane's own ch7
    float pm = (p < np) ? 1.f : 0.f;
    float cm = (fl > 0.5f) ? pm : 0.f;
    float hm = pm - cm;
    cc += cm; hc += hm;
    s[0] += x.x*cm; s[1] += x.y*cm; s[2] += x.z*cm; s[3] += x.w*cm;
    h[0] += x.x*hm; h[1] += x.y*hm; h[2] += x.z*hm; h[3] += x.w*hm;
  }
  #pragma unroll
  for (int o = 2; o <= 4; o <<= 1){
    cc += __shfl_xor(cc, o); hc += __shfl_xor(hc, o);
    #pragma unroll
    for (int q = 0; q < 4; ++q){
      s[q] += __shfl_xor(s[q], o);
      h[q] += __shfl_xor(h[q], o);
    }
  }
  const float icc = 1.f / fmaxf(cc, 1.f);
  const float ihc = 1.f / fmaxf(hc, 1.f);
  unsigned short* mp = means + (size_t)v*16;   // [cur 0-7 | his 0-7] bf16
  if (j < 2){
    ushort4 w;
    w.x = f2bf(s[0]*icc); w.y = f2bf(s[1]*icc);
    w.z = f2bf(s[2]*icc); w.w = f2bf(s[3]*icc);
    *(ushort4*)(mp + j*4) = w;               // j=0: cur ch0-3, j=1: cur ch4-7
  } else if (j < 4){
    ushort4 w;
    w.x = f2bf(h[0]*ihc); w.y = f2bf(h[1]*ihc);
    w.z = f2bf(h[2]*ihc); w.w = f2bf(h[3]*ihc);
    *(ushort4*)(mp + 8 + (j-2)*4) = w;       // j=2: his ch0-3, j=3: his ch4-7
  } else if (j == 4){
    flags[v] = (cc > 0.f ? 1 : 0) | (hc > 0.f ? 2 : 0);
  }
}

// ---------------- main kernel (R6 body, aggregation replaced) -------------
__global__ __launch_bounds__(256)
void tva_main(const float* __restrict__ vf,
              const unsigned short* __restrict__ means, const int* __restrict__ flags,
              const float* __restrict__ pp_b1, const float* __restrict__ pp_b2,
              const float* __restrict__ ipb,  const float* __restrict__ outb,
              const float* __restrict__ ln1g, const float* __restrict__ ln1b,
              const float* __restrict__ f1b,  const float* __restrict__ f2bv,
              const float* __restrict__ ln2g, const float* __restrict__ ln2b,
              const float* __restrict__ o1b,  const float* __restrict__ o2b,
              const unsigned short* __restrict__ wfrag,
              float* __restrict__ out, int nvox)
{
  __shared__ unsigned short smem[4 * 64 * 64];   // 32 KB: 4 waves x 8 KB
  const int tid  = threadIdx.x;
  const int wv   = tid >> 6;
  const int lane = tid & 63;
  unsigned short* X = smem + wv * (64*64);  // rows 0..47: tok12 -> K -> V -> ffn-h -> op1-h
  unsigned short* Q = X + 48*64;            // rows 0..15: q -> ctx -> postLN1 -> postLN2

  const int v0 = (blockIdx.x * 4 + wv) * 16;
  if (v0 >= nvox) return;                   // tail waves (no barriers -> safe)
  const int cl = lane & 15;
  const int r0 = (lane >> 4) << 2;

  // ======== Phase A': load precomputed means + flags ========
  const int fwv = flags[v0 + cl];           // voxel cl's {cur_any, his_present}
  bf16x8 ac, ah;
  {
    union { bf16x8 v; unsigned short u[8]; } z;
    #pragma unroll
    for (int i = 0; i < 8; ++i) z.u[i] = 0;
    ac = z.v; ah = z.v;
    if (lane < 16){
      const unsigned short* mp = means + (size_t)(v0 + cl)*16;
      ac = *(const bf16x8*)mp;              // cur means ch0-7 (k-pad 8..31 = 0)
      ah = *(const bf16x8*)(mp + 8);        // his means ch0-7
    }
  }

  // ======== Phase B: point_proj (8->64 relu, 64->64) ========
  #pragma unroll
  for (int nt = 0; nt < 4; ++nt){
    float bb = pp_b1[nt*16 + cl];
    f32x4 c0 = {bb, bb, bb, bb}, c1 = {bb, bb, bb, bb};
    bf16x8 B = ldB(wfrag, nt, lane);
    c0 = MF(ac, B, c0);
    c1 = MF(ah, B, c1);
    #pragma unroll
    for (int r = 0; r < 4; ++r){ c0[r] = fmaxf(c0[r], 0.f); c1[r] = fmaxf(c1[r], 0.f); }
    stC(X, 0, nt, c0, lane);   // hidden(cur) rows 0..15
    stC(X, 1, nt, c1, lane);   // hidden(his) rows 16..31
  }
  {
    bf16x8 hfr[2][2];
    #pragma unroll
    for (int m = 0; m < 2; ++m)
      #pragma unroll
      for (int kt = 0; kt < 2; ++kt) hfr[m][kt] = ldA(X, m, kt, lane);
    // loads precede the overwriting stores in program order (per-wave LDS order)
    #pragma unroll
    for (int m = 0; m < 2; ++m){
      #pragma unroll
      for (int nt = 0; nt < 4; ++nt){
        float bb = pp_b2[nt*16 + cl];
        f32x4 c = {bb, bb, bb, bb};
        c = MF(hfr[m][0], ldB(wfrag, 4 + nt*2 + 0, lane), c);
        c = MF(hfr[m][1], ldB(wfrag, 4 + nt*2 + 1, lane), c);
        stC(X, m, nt, c, lane);   // token1 rows 0..15, token2 rows 16..31
      }
    }
  }

  // ======== Phase C: QKV projections ========
  bf16x8 at[3][2];
  {
    // token0 A-frags straight from global vf (f32 -> bf16)
    const float* s = vf + (size_t)(v0 + cl) * 64 + ((lane >> 4) << 3);
    #pragma unroll
    for (int kt = 0; kt < 2; ++kt){
      float4 x0 = *(const float4*)(s + kt*32);
      float4 x1 = *(const float4*)(s + kt*32 + 4);
      float f[8] = {x0.x, x0.y, x0.z, x0.w, x1.x, x1.y, x1.z, x1.w};
      at[0][kt] = pack8(f);
    }
    #pragma unroll
    for (int kt = 0; kt < 2; ++kt){
      at[1][kt] = ldA(X, 0, kt, lane);
      at[2][kt] = ldA(X, 1, kt, lane);
    }
  }
  // q (token0 rows only), pre-scaled by 1/sqrt(DH)=0.25 -> Q
  #pragma unroll
  for (int nt = 0; nt < 4; ++nt){
    float bb = ipb[nt*16 + cl];
    f32x4 c = {bb, bb, bb, bb};
    c = MF(at[0][0], ldB(wfrag, 12 + nt*2 + 0, lane), c);
    c = MF(at[0][1], ldB(wfrag, 12 + nt*2 + 1, lane), c);
    #pragma unroll
    for (int r = 0; r < 4; ++r) c[r] *= 0.25f;
    stC(Q, 0, nt, c, lane);
  }
  // K (3 tokens) -> X rows 0..47 (token1/2 A-frags already in regs)
  #pragma unroll
  for (int m = 0; m < 3; ++m){
    #pragma unroll
    for (int nt = 0; nt < 4; ++nt){
      int ntg = 4 + nt;
      float bb = ipb[64 + nt*16 + cl];
      f32x4 c = {bb, bb, bb, bb};
      c = MF(at[m][0], ldB(wfrag, 12 + ntg*2 + 0, lane), c);
      c = MF(at[m][1], ldB(wfrag, 12 + ntg*2 + 1, lane), c);
      stC(X, m, nt, c, lane);
    }
  }

  // ======== Phase D1: scores + softmax (lane = (voxel, head)) ========
  const int av = cl, hh2 = lane >> 4;
  float p0, p1, p2;
  {
    bool caZ = (fwv & 1) != 0, hpZ = (fwv & 2) != 0;
    float q[16]; ld16(Q, av, hh2*16, q);
    float sc[3];
    #pragma unroll
    for (int m = 0; m < 3; ++m){
      float kv[16]; ld16(X, m*16 + av, hh2*16, kv);
      float d = 0.f;
      #pragma unroll
      for (int j = 0; j < 16; ++j) d += q[j]*kv[j];
      sc[m] = d;
    }
    float mx = sc[0];
    mx = caZ ? fmaxf(mx, sc[1]) : mx;
    mx = hpZ ? fmaxf(mx, sc[2]) : mx;
    float e0 = __expf(sc[0] - mx);
    float e1 = caZ ? __expf(sc[1] - mx) : 0.f;
    float e2 = hpZ ? __expf(sc[2] - mx) : 0.f;
    float inv = 1.f / (e0 + e1 + e2);
    p0 = e0*inv; p1 = e1*inv; p2 = e2*inv;
  }

  // ======== Phase C2: V projection -> X (K reads precede in program order) ====
  #pragma unroll
  for (int m = 0; m < 3; ++m){
    #pragma unroll
    for (int nt = 0; nt < 4; ++nt){
      int ntg = 8 + nt;
      float bb = ipb[128 + nt*16 + cl];
      f32x4 c = {bb, bb, bb, bb};
      c = MF(at[m][0], ldB(wfrag, 12 + ntg*2 + 0, lane), c);
      c = MF(at[m][1], ldB(wfrag, 12 + ntg*2 + 1, lane), c);
      stC(X, m, nt, c, lane);
    }
  }

  // ======== Phase D2: ctx = p . V  -> Q (overwrites q) ========
  {
    float ctx[16];
    float vv[16];
    ld16(X, av, hh2*16, vv);
    #pragma unroll
    for (int j = 0; j < 16; ++j) ctx[j] = p0*vv[j];
    ld16(X, 16 + av, hh2*16, vv);
    #pragma unroll
    for (int j = 0; j < 16; ++j) ctx[j] += p1*vv[j];
    ld16(X, 32 + av, hh2*16, vv);
    #pragma unroll
    for (int j = 0; j < 16; ++j) ctx[j] += p2*vv[j];
    st16(Q, av, hh2*16, ctx);
  }

  // ======== Phase E: attn_out + residual + LN1 (token0 only) ========
  f32x4 res1[4];
  {
    bf16x8 a0 = ldA(Q, 0, 0, lane), a1 = ldA(Q, 0, 1, lane);
    float rv[16];
    #pragma unroll
    for (int nt = 0; nt < 4; ++nt)
      #pragma unroll
      for (int r = 0; r < 4; ++r)
        rv[nt*4 + r] = vf[(size_t)(v0 + r0 + r)*64 + nt*16 + cl];
    #pragma unroll
    for (int nt = 0; nt < 4; ++nt){
      float bb = outb[nt*16 + cl];
      f32x4 c = {bb, bb, bb, bb};
      c = MF(a0, ldB(wfrag, 36 + nt*2 + 0, lane), c);
      c = MF(a1, ldB(wfrag, 36 + nt*2 + 1, lane), c);
      #pragma unroll
      for (int r = 0; r < 4; ++r) c[r] += rv[nt*4 + r];
      res1[nt] = c;
    }
    layer_norm16(res1, ln1g, ln1b, lane);
    #pragma unroll
    for (int nt = 0; nt < 4; ++nt) stC(Q, 0, nt, res1[nt], lane);
  }

  // ======== Phase F: FFN (64->128 relu ->64) + residual + LN2 ========
  f32x4 tk2[4];
  {
    bf16x8 a0 = ldA(Q, 0, 0, lane), a1 = ldA(Q, 0, 1, lane);
    #pragma unroll
    for (int nt = 0; nt < 4; ++nt){
      float bb = f2bv[nt*16 + cl];
      tk2[nt] = (f32x4){bb, bb, bb, bb};
    }
    // h cols 0..63
    #pragma unroll
    for (int nt = 0; nt < 4; ++nt){
      float bb = f1b[nt*16 + cl];
      f32x4 c = {bb, bb, bb, bb};
      c = MF(a0, ldB(wfrag, 44 + nt*2 + 0, lane), c);
      c = MF(a1, ldB(wfrag, 44 + nt*2 + 1, lane), c);
      #pragma unroll
      for (int r = 0; r < 4; ++r) c[r] = fmaxf(c[r], 0.f);
      stC(X, 0, nt, c, lane);
    }
    {
      bf16x8 h0 = ldA(X, 0, 0, lane), h1 = ldA(X, 0, 1, lane);
      #pragma unroll
      for (int nt = 0; nt < 4; ++nt){
        tk2[nt] = MF(h0, ldB(wfrag, 60 + nt*4 + 0, lane), tk2[nt]);
        tk2[nt] = MF(h1, ldB(wfrag, 60 + nt*4 + 1, lane), tk2[nt]);
      }
    }
    // h cols 64..127 (h0/h1 loads precede these stores in program order)
    #pragma unroll
    for (int nt = 4; nt < 8; ++nt){
      float bb = f1b[nt*16 + cl];
      f32x4 c = {bb, bb, bb, bb};
      c = MF(a0, ldB(wfrag, 44 + nt*2 + 0, lane), c);
      c = MF(a1, ldB(wfrag, 44 + nt*2 + 1, lane), c);
      #pragma unroll
      for (int r = 0; r < 4; ++r) c[r] = fmaxf(c[r], 0.f);
      stC(X, 0, nt - 4, c, lane);
    }
    {
      bf16x8 h0 = ldA(X, 0, 0, lane), h1 = ldA(X, 0, 1, lane);
      #pragma unroll
      for (int nt = 0; nt < 4; ++nt){
        tk2[nt] = MF(h0, ldB(wfrag, 60 + nt*4 + 2, lane), tk2[nt]);
        tk2[nt] = MF(h1, ldB(wfrag, 60 + nt*4 + 3, lane), tk2[nt]);
      }
    }
    #pragma unroll
    for (int nt = 0; nt < 4; ++nt)
      #pragma unroll
      for (int r = 0; r < 4; ++r) tk2[nt][r] += res1[nt][r];
    layer_norm16(tk2, ln2g, ln2b, lane);
    #pragma unroll
    for (int nt = 0; nt < 4; ++nt) stC(Q, 0, nt, tk2[nt], lane);
  }

  // ======== Phase G: output MLP + gate + final residual ========
  {
    bf16x8 a0 = ldA(Q, 0, 0, lane), a1 = ldA(Q, 0, 1, lane);
    #pragma unroll
    for (int nt = 0; nt < 4; ++nt){
      float bb = o1b[nt*16 + cl];
      f32x4 c = {bb, bb, bb, bb};
      c = MF(a0, ldB(wfrag, 76 + nt*2 + 0, lane), c);
      c = MF(a1, ldB(wfrag, 76 + nt*2 + 1, lane), c);
      #pragma unroll
      for (int r = 0; r < 4; ++r) c[r] = fmaxf(c[r], 0.f);
      stC(X, 0, nt, c, lane);
    }
    bf16x8 b0 = ldA(X, 0, 0, lane), b1 = ldA(X, 0, 1, lane);
    #pragma unroll
    for (int nt = 0; nt < 4; ++nt){
      float bb = o2b[nt*16 + cl];
      f32x4 c = {bb, bb, bb, bb};
      c = MF(b0, ldB(wfrag, 84 + nt*2 + 0, lane), c);
      c = MF(b1, ldB(wfrag, 84 + nt*2 + 1, lane), c);
      #pragma unroll
      for (int r = 0; r < 4; ++r){
        int row = r0 + r;
        int fwr = flags[v0 + row];                  // voxel (v0+row) flags
        float keep = (fwr & 2) ? 1.f : 0.f;         // history_present gate
        size_t idx = (size_t)(v0 + row)*64 + nt*16 + cl;
        out[idx] = vf[idx] + keep * c[r];
      }
    }
  }
}

extern "C" void kernel_launch(void* const* d_in, const int* in_sizes, int n_in,
                              void* d_out, int out_size, void* d_ws, size_t ws_size,
                              hipStream_t stream)
{
  (void)n_in; (void)out_size; (void)ws_size;
  const float* vf    = (const float*)d_in[0];
  const float* vox   = (const float*)d_in[1];
  const float* pp_w1 = (const float*)d_in[2];
  const float* pp_b1 = (const float*)d_in[3];
  const float* pp_w2 = (const float*)d_in[4];
  const float* pp_b2 = (const float*)d_in[5];
  const float* ipw   = (const float*)d_in[6];
  const float* ipb   = (const float*)d_in[7];
  const float* outw  = (const float*)d_in[8];
  const float* outb  = (const float*)d_in[9];
  const float* ln1g  = (const float*)d_in[10];
  const float* ln1b  = (const float*)d_in[11];
  const float* f1w   = (const float*)d_in[12];
  const float* f1b   = (const float*)d_in[13];
  const float* f2w   = (const float*)d_in[14];
  const float* f2b   = (const float*)d_in[15];
  const float* ln2g  = (const float*)d_in[16];
  const float* ln2b  = (const float*)d_in[17];
  const float* o1w   = (const float*)d_in[18];
  const float* o1b   = (const float*)d_in[19];
  const float* o2w   = (const float*)d_in[20];
  const float* o2b   = (const float*)d_in[21];
  const int*   npts  = (const int*)d_in[22];
  float* out = (float*)d_out;

  const int nvox = in_sizes[0] / 64;                 // 100000
  // d_ws layout: wfrag 94208 B | means bf16[nvox][16] | flags int[nvox]
  unsigned short* wfrag = (unsigned short*)d_ws;
  unsigned short* means = (unsigned short*)((char*)d_ws + 94208);
  int*            flags = (int*)((char*)d_ws + 94208 + (size_t)nvox*32);

  const int nblkA = (nvox + 31) / 32;                // 3125: 4 waves x 8 voxels
  const int ngrp  = (nvox + 15) / 16;                // 6250 wave-groups
  const int nblkB = (ngrp + 3) / 4;                  // 1563 blocks x 4 waves

  tva_pack_weights<<<92, 64, 0, stream>>>(pp_w1, pp_w2, ipw, outw, f1w, f2w, o1w, o2w, wfrag);
  tva_aggregate<<<nblkA, 256, 0, stream>>>(vox, npts, means, flags, nvox);
  tva_main<<<nblkB, 256, 0, stream>>>(vf, means, flags, pp_b1, pp_b2, ipb, outb,
                                      ln1g, ln1b, f1b, f2b, ln2g, ln2b, o1b, o2b,
                                      wfrag, out, nvox);
}

// Round 10
// 72.243 us; speedup vs baseline: 1.1707x; 1.1238x over previous
//
#include <hip/hip_runtime.h>

// TemporalVoxelAttention — MFMA (bf16) fused.
// R10: R6's fence-free fused kernel, block geometry 2 waves x 64 thr (16 KB
// LDS/block). Occupancy-quantization model from R1-R9: resident blocks/CU =
// min(~8 WG slots, VGPR 4waves/SIMD, LDS). 4-wave WGs cap at 4 blocks=16w
// but 6.1 blocks/CU of work -> 1.53 quantized rounds of a 35us block = 75us.
// 2-wave WGs: min(8 slots, 8 blocks@VGPR<=128, 10 blocks@16KB) = 8 blocks =
// 16 waves/CU with 12.2 blocks/CU of work -> 1.53 rounds of a ~20us block.
// R2-R4 were 2-wave but spill/fence-crippled; this geometry never ran clean.
// d_ws holds weights pre-packed into MFMA B-fragment layout (94208 B).

using bf16x8 = __attribute__((ext_vector_type(8))) __bf16;
using f32x4  = __attribute__((ext_vector_type(4))) float;

#define DEV static __device__ __forceinline__

DEV float bf2f(unsigned short u){
  union { unsigned int i; float f; } v; v.i = ((unsigned int)u) << 16; return v.f;
}
DEV unsigned short f2bf(float f){
  union { float f; unsigned int i; } v; v.f = f;
  unsigned int x = v.i;
  x += 0x7FFFu + ((x >> 16) & 1u);           // RNE to bf16 (inputs finite)
  return (unsigned short)(x >> 16);
}

// LDS matrices: [rows][64] bf16 (128-B rows), XOR-swizzle byte ^= ((row&7)<<4).
DEV unsigned short* lp(unsigned short* base, int row, int col){
  int byte = (col << 1) ^ ((row & 7) << 4);
  return (unsigned short*)((char*)base + (row << 7) + byte);
}

// A-fragment: lane holds A[row = mt*16 + (lane&15)][k = kt*32 + (lane>>4)*8 + i]
DEV bf16x8 ldA(const unsigned short* base, int mt, int kt, int lane){
  int row = mt*16 + (lane & 15);
  int col = kt*32 + ((lane >> 4) << 3);
  return *(const bf16x8*)lp((unsigned short*)base, row, col);
}
// B-fragment: pre-packed in ws, lane-contiguous 16B
DEV bf16x8 ldB(const unsigned short* w, int frag, int lane){
  return *(const bf16x8*)(w + (size_t)frag*512 + (size_t)lane*8);
}
// C/D: col = lane&15, row = mt*16 + (lane>>4)*4 + r
DEV void stC(unsigned short* base, int mt, int nt, f32x4 c, int lane){
  int col  = nt*16 + (lane & 15);
  int row0 = mt*16 + ((lane >> 4) << 2);
  #pragma unroll
  for (int r = 0; r < 4; ++r) *lp(base, row0 + r, col) = f2bf(c[r]);
}
DEV f32x4 MF(bf16x8 a, bf16x8 b, f32x4 c){
  return __builtin_amdgcn_mfma_f32_16x16x32_bf16(a, b, c, 0, 0, 0);
}

DEV void ld16(const unsigned short* base, int row, int col0, float* o){
  uint4 a = *(const uint4*)lp((unsigned short*)base, row, col0);
  uint4 b = *(const uint4*)lp((unsigned short*)base, row, col0 + 8);
  unsigned int w[8] = {a.x, a.y, a.z, a.w, b.x, b.y, b.z, b.w};
  #pragma unroll
  for (int i = 0; i < 8; ++i){
    union { unsigned int u; float f; } lo, hi;
    lo.u = w[i] << 16; hi.u = w[i] & 0xFFFF0000u;
    o[2*i] = lo.f; o[2*i+1] = hi.f;
  }
}
DEV void st16(unsigned short* base, int row, int col0, const float* f){
  unsigned int w[8];
  #pragma unroll
  for (int i = 0; i < 8; ++i)
    w[i] = (unsigned int)f2bf(f[2*i]) | ((unsigned int)f2bf(f[2*i+1]) << 16);
  *(uint4*)lp(base, row, col0)     = make_uint4(w[0], w[1], w[2], w[3]);
  *(uint4*)lp(base, row, col0 + 8) = make_uint4(w[4], w[5], w[6], w[7]);
}

DEV bf16x8 pack8(const float* f){
  union { bf16x8 v; unsigned short u[8]; } r;
  #pragma unroll
  for (int i = 0; i < 8; ++i) r.u[i] = f2bf(f[i]);
  return r.v;
}

// LayerNorm over 64 cols for one 16-row M-tile held as 4 C-frags.
DEV void layer_norm16(f32x4 x[4], const float* g, const float* b, int lane){
  float s[4], s2[4];
  #pragma unroll
  for (int r = 0; r < 4; ++r){
    s[r]  = x[0][r] + x[1][r] + x[2][r] + x[3][r];
    s2[r] = x[0][r]*x[0][r] + x[1][r]*x[1][r] + x[2][r]*x[2][r] + x[3][r]*x[3][r];
  }
  #pragma unroll
  for (int o = 1; o <= 8; o <<= 1){
    #pragma unroll
    for (int r = 0; r < 4; ++r){
      s[r]  += __shfl_xor(s[r],  o);
      s2[r] += __shfl_xor(s2[r], o);
    }
  }
  float mu[4], rs[4];
  #pragma unroll
  for (int r = 0; r < 4; ++r){
    mu[r] = s[r] * (1.f/64.f);
    float var = s2[r] * (1.f/64.f) - mu[r]*mu[r];
    rs[r] = rsqrtf(var + 1e-5f);
  }
  const int cl = lane & 15;
  #pragma unroll
  for (int nt = 0; nt < 4; ++nt){
    float gg = g[nt*16 + cl], bb = b[nt*16 + cl];
    #pragma unroll
    for (int r = 0; r < 4; ++r)
      x[nt][r] = (x[nt][r] - mu[r]) * rs[r] * gg + bb;
  }
}

// ---------------- weight packing (unchanged) ----------------
// 0: pp_w1 (K=8 pad 32, N=64)   base 0,  4 frags
// 1: pp_w2 (K=64,  N=64)        base 4,  8
// 2: in_proj (K=64, N=192)      base 12, 24
// 3: out_w (K=64, N=64)         base 36, 8
// 4: ffn_w1 (K=64, N=128)       base 44, 16
// 5: ffn_w2 (K=128, N=64)       base 60, 16
// 6: op_w1 (K=64, N=64)         base 76, 8
// 7: op_w2 (K=64, N=64)         base 84, 8   -> 92 frags total
__global__ void tva_pack_weights(const float* __restrict__ pp_w1, const float* __restrict__ pp_w2,
                                 const float* __restrict__ in_proj_w, const float* __restrict__ out_w,
                                 const float* __restrict__ ffn_w1, const float* __restrict__ ffn_w2,
                                 const float* __restrict__ op_w1, const float* __restrict__ op_w2,
                                 unsigned short* __restrict__ ws)
{
  int b = blockIdx.x, lane = threadIdx.x;
  const float* W; int base, ktiles, K;
  if      (b < 4)  { W = pp_w1;     base = 0;  ktiles = 1; K = 8;   }
  else if (b < 12) { W = pp_w2;     base = 4;  ktiles = 2; K = 64;  }
  else if (b < 36) { W = in_proj_w; base = 12; ktiles = 2; K = 64;  }
  else if (b < 44) { W = out_w;     base = 36; ktiles = 2; K = 64;  }
  else if (b < 60) { W = ffn_w1;    base = 44; ktiles = 2; K = 64;  }
  else if (b < 76) { W = ffn_w2;    base = 60; ktiles = 4; K = 128; }
  else if (b < 84) { W = op_w1;     base = 76; ktiles = 2; K = 64;  }
  else             { W = op_w2;     base = 84; ktiles = 2; K = 64;  }
  int local = b - base;
  int nt = local / ktiles, kt = local % ktiles;
  int n  = nt*16 + (lane & 15);
  int k0 = kt*32 + ((lane >> 4) << 3);
  unsigned short* dst = ws + (size_t)b*512 + (size_t)lane*8;
  #pragma unroll
  for (int i = 0; i < 8; ++i){
    int k = k0 + i;
    float v = (k < K) ? W[(size_t)n*K + k] : 0.0f;
    dst[i] = f2bf(v);
  }
}

// ---------------- main kernel ----------------
__global__ __launch_bounds__(128)
void tva_main(const float* __restrict__ vf, const float* __restrict__ vox,
              const int* __restrict__ num_points,
              const float* __restrict__ pp_b1, const float* __restrict__ pp_b2,
              const float* __restrict__ ipb,  const float* __restrict__ outb,
              const float* __restrict__ ln1g, const float* __restrict__ ln1b,
              const float* __restrict__ f1b,  const float* __restrict__ f2bv,
              const float* __restrict__ ln2g, const float* __restrict__ ln2b,
              const float* __restrict__ o1b,  const float* __restrict__ o2b,
              const unsigned short* __restrict__ wfrag,
              float* __restrict__ out, int nvox)
{
  __shared__ unsigned short smem[2 * 64 * 64];   // 16 KB: 2 waves x 8 KB
  const int tid  = threadIdx.x;
  const int wv   = tid >> 6;
  const int lane = tid & 63;
  unsigned short* X = smem + wv * (64*64);  // rows 0..47: hidden -> tok12 -> K -> V -> ffn-h -> op1-h
  unsigned short* Q = X + 48*64;            // rows 0..15: q -> ctx -> postLN1 -> postLN2

  const int v0 = (blockIdx.x * 2 + wv) * 16;
  if (v0 >= nvox) return;                   // tail waves (no barriers -> safe)
  const int cl = lane & 15;
  const int r0 = (lane >> 4) << 2;

  // ======== Phase A: point aggregation (4 lanes per voxel) ========
  const int vi = lane >> 2, pq = lane & 3;
  const int np = num_points[v0 + vi];
  float cs[8] = {0,0,0,0,0,0,0,0}, hs[8] = {0,0,0,0,0,0,0,0};
  float cc = 0.f, hc = 0.f;
  const float4* vp = (const float4*)(vox + (size_t)(v0 + vi) * 384);
  #pragma unroll
  for (int k = 0; k < 12; ++k){
    int p = pq + (k << 2);
    float4 a = vp[p*2], b = vp[p*2 + 1];
    float pm = (p < np) ? 1.f : 0.f;
    float cm = (b.w > 0.5f) ? pm : 0.f;   // current: flag>0.5 & in-range
    float hm = pm - cm;                   // history: in-range & !current
    cc += cm; hc += hm;
    cs[0] += a.x*cm; cs[1] += a.y*cm; cs[2] += a.z*cm; cs[3] += a.w*cm;
    cs[4] += b.x*cm; cs[5] += b.y*cm; cs[6] += b.z*cm; cs[7] += b.w*cm;
    hs[0] += a.x*hm; hs[1] += a.y*hm; hs[2] += a.z*hm; hs[3] += a.w*hm;
    hs[4] += b.x*hm; hs[5] += b.y*hm; hs[6] += b.z*hm; hs[7] += b.w*hm;
  }
  #pragma unroll
  for (int o = 1; o <= 2; o <<= 1){
    cc += __shfl_xor(cc, o); hc += __shfl_xor(hc, o);
    #pragma unroll
    for (int j = 0; j < 8; ++j){
      cs[j] += __shfl_xor(cs[j], o);
      hs[j] += __shfl_xor(hs[j], o);
    }
  }
  const float icc = 1.f / fmaxf(cc, 1.f);
  const float ihc = 1.f / fmaxf(hc, 1.f);
  const unsigned int myfw = (cc > 0.f ? 1u : 0u) | (hc > 0.f ? 2u : 0u);

  // Build pp-GEMM1 A-fragments in-register (16 shuffles; no LDS staging).
  // A[row=voxel][k=channel 0..7, pad to 32]: lanes 0..15 hold real data.
  bf16x8 ac, ah;
  {
    const int src = cl * 4;   // any lane of voxel (lane&15) has the full sums
    float cf[8], hf[8];
    #pragma unroll
    for (int i = 0; i < 8; ++i){
      cf[i] = __shfl(cs[i]*icc, src);
      hf[i] = __shfl(hs[i]*ihc, src);
    }
    union { bf16x8 v; unsigned short u[8]; } rc, rh;
    #pragma unroll
    for (int i = 0; i < 8; ++i){
      rc.u[i] = (lane < 16) ? f2bf(cf[i]) : (unsigned short)0;
      rh.u[i] = (lane < 16) ? f2bf(hf[i]) : (unsigned short)0;
    }
    ac = rc.v; ah = rh.v;
  }

  // ======== Phase B: point_proj (8->64 relu, 64->64) ========
  #pragma unroll
  for (int nt = 0; nt < 4; ++nt){
    float bb = pp_b1[nt*16 + cl];
    f32x4 c0 = {bb, bb, bb, bb}, c1 = {bb, bb, bb, bb};
    bf16x8 B = ldB(wfrag, nt, lane);
    c0 = MF(ac, B, c0);
    c1 = MF(ah, B, c1);
    #pragma unroll
    for (int r = 0; r < 4; ++r){ c0[r] = fmaxf(c0[r], 0.f); c1[r] = fmaxf(c1[r], 0.f); }
    stC(X, 0, nt, c0, lane);   // hidden(cur) rows 0..15
    stC(X, 1, nt, c1, lane);   // hidden(his) rows 16..31
  }
  {
    bf16x8 hfr[2][2];
    #pragma unroll
    for (int m = 0; m < 2; ++m)
      #pragma unroll
      for (int kt = 0; kt < 2; ++kt) hfr[m][kt] = ldA(X, m, kt, lane);
    // loads precede the overwriting stores in program order; per-wave LDS
    // pipe is in-order, so no fence needed before reusing rows 0..31.
    #pragma unroll
    for (int m = 0; m < 2; ++m){
      #pragma unroll
      for (int nt = 0; nt < 4; ++nt){
        float bb = pp_b2[nt*16 + cl];
        f32x4 c = {bb, bb, bb, bb};
        c = MF(hfr[m][0], ldB(wfrag, 4 + nt*2 + 0, lane), c);
        c = MF(hfr[m][1], ldB(wfrag, 4 + nt*2 + 1, lane), c);
        stC(X, m, nt, c, lane);   // token1 rows 0..15, token2 rows 16..31
      }
    }
  }

  // ======== Phase C: QKV projections ========
  bf16x8 at[3][2];
  {
    // token0 A-frags straight from global vf (f32 -> bf16)
    const float* s = vf + (size_t)(v0 + cl) * 64 + ((lane >> 4) << 3);
    #pragma unroll
    for (int kt = 0; kt < 2; ++kt){
      float4 x0 = *(const float4*)(s + kt*32);
      float4 x1 = *(const float4*)(s + kt*32 + 4);
      float f[8] = {x0.x, x0.y, x0.z, x0.w, x1.x, x1.y, x1.z, x1.w};
      at[0][kt] = pack8(f);
    }
    #pragma unroll
    for (int kt = 0; kt < 2; ++kt){
      at[1][kt] = ldA(X, 0, kt, lane);
      at[2][kt] = ldA(X, 1, kt, lane);
    }
  }
  // q (token0 rows only), pre-scaled by 1/sqrt(DH)=0.25 -> Q
  #pragma unroll
  for (int nt = 0; nt < 4; ++nt){
    float bb = ipb[nt*16 + cl];
    f32x4 c = {bb, bb, bb, bb};
    c = MF(at[0][0], ldB(wfrag, 12 + nt*2 + 0, lane), c);
    c = MF(at[0][1], ldB(wfrag, 12 + nt*2 + 1, lane), c);
    #pragma unroll
    for (int r = 0; r < 4; ++r) c[r] *= 0.25f;
    stC(Q, 0, nt, c, lane);
  }
  // K (3 tokens) -> X rows 0..47 (token1/2 A-frags already in regs)
  #pragma unroll
  for (int m = 0; m < 3; ++m){
    #pragma unroll
    for (int nt = 0; nt < 4; ++nt){
      int ntg = 4 + nt;
      float bb = ipb[64 + nt*16 + cl];
      f32x4 c = {bb, bb, bb, bb};
      c = MF(at[m][0], ldB(wfrag, 12 + ntg*2 + 0, lane), c);
      c = MF(at[m][1], ldB(wfrag, 12 + ntg*2 + 1, lane), c);
      stC(X, m, nt, c, lane);
    }
  }

  // ======== Phase D1: scores + softmax (lane = (voxel, head)) ========
  const int av = cl, hh2 = lane >> 4;
  float p0, p1, p2;
  {
    unsigned int fw = (unsigned int)__shfl((int)myfw, av*4);
    bool caZ = (fw & 1u) != 0, hpZ = (fw & 2u) != 0;
    float q[16]; ld16(Q, av, hh2*16, q);
    float sc[3];
    #pragma unroll
    for (int m = 0; m < 3; ++m){
      float kv[16]; ld16(X, m*16 + av, hh2*16, kv);
      float d = 0.f;
      #pragma unroll
      for (int j = 0; j < 16; ++j) d += q[j]*kv[j];
      sc[m] = d;
    }
    float mx = sc[0];
    mx = caZ ? fmaxf(mx, sc[1]) : mx;
    mx = hpZ ? fmaxf(mx, sc[2]) : mx;
    p0 = __expf(sc[0] - mx);
    p1 = caZ ? __expf(sc[1] - mx) : 0.f;
    p2 = hpZ ? __expf(sc[2] - mx) : 0.f;
    float inv = 1.f / (p0 + p1 + p2);
    p0 *= inv; p1 *= inv; p2 *= inv;
  }

  // ======== Phase C2: V projection -> X (K reads precede in program order) ========
  #pragma unroll
  for (int m = 0; m < 3; ++m){
    #pragma unroll
    for (int nt = 0; nt < 4; ++nt){
      int ntg = 8 + nt;
      float bb = ipb[128 + nt*16 + cl];
      f32x4 c = {bb, bb, bb, bb};
      c = MF(at[m][0], ldB(wfrag, 12 + ntg*2 + 0, lane), c);
      c = MF(at[m][1], ldB(wfrag, 12 + ntg*2 + 1, lane), c);
      stC(X, m, nt, c, lane);
    }
  }

  // ======== Phase D2: ctx = p . V  -> Q (overwrites q) ========
  {
    float ctx[16];
    float vv[16];
    ld16(X, av, hh2*16, vv);
    #pragma unroll
    for (int j = 0; j < 16; ++j) ctx[j] = p0*vv[j];
    ld16(X, 16 + av, hh2*16, vv);
    #pragma unroll
    for (int j = 0; j < 16; ++j) ctx[j] += p1*vv[j];
    ld16(X, 32 + av, hh2*16, vv);
    #pragma unroll
    for (int j = 0; j < 16; ++j) ctx[j] += p2*vv[j];
    st16(Q, av, hh2*16, ctx);
  }

  // ======== Phase E: attn_out + residual + LN1 (token0 only) ========
  f32x4 res1[4];
  {
    bf16x8 a0 = ldA(Q, 0, 0, lane), a1 = ldA(Q, 0, 1, lane);
    float rv[16];
    #pragma unroll
    for (int nt = 0; nt < 4; ++nt)
      #pragma unroll
      for (int r = 0; r < 4; ++r)
        rv[nt*4 + r] = vf[(size_t)(v0 + r0 + r)*64 + nt*16 + cl];
    #pragma unroll
    for (int nt = 0; nt < 4; ++nt){
      float bb = outb[nt*16 + cl];
      f32x4 c = {bb, bb, bb, bb};
      c = MF(a0, ldB(wfrag, 36 + nt*2 + 0, lane), c);
      c = MF(a1, ldB(wfrag, 36 + nt*2 + 1, lane), c);
      #pragma unroll
      for (int r = 0; r < 4; ++r) c[r] += rv[nt*4 + r];
      res1[nt] = c;
    }
    layer_norm16(res1, ln1g, ln1b, lane);
    #pragma unroll
    for (int nt = 0; nt < 4; ++nt) stC(Q, 0, nt, res1[nt], lane);
  }

  // ======== Phase F: FFN (64->128 relu ->64) + residual + LN2 ========
  f32x4 tk2[4];
  {
    bf16x8 a0 = ldA(Q, 0, 0, lane), a1 = ldA(Q, 0, 1, lane);
    #pragma unroll
    for (int nt = 0; nt < 4; ++nt){
      float bb = f2bv[nt*16 + cl];
      tk2[nt] = (f32x4){bb, bb, bb, bb};
    }
    // h cols 0..63
    #pragma unroll
    for (int nt = 0; nt < 4; ++nt){
      float bb = f1b[nt*16 + cl];
      f32x4 c = {bb, bb, bb, bb};
      c = MF(a0, ldB(wfrag, 44 + nt*2 + 0, lane), c);
      c = MF(a1, ldB(wfrag, 44 + nt*2 + 1, lane), c);
      #pragma unroll
      for (int r = 0; r < 4; ++r) c[r] = fmaxf(c[r], 0.f);
      stC(X, 0, nt, c, lane);
    }
    {
      bf16x8 h0 = ldA(X, 0, 0, lane), h1 = ldA(X, 0, 1, lane);
      #pragma unroll
      for (int nt = 0; nt < 4; ++nt){
        tk2[nt] = MF(h0, ldB(wfrag, 60 + nt*4 + 0, lane), tk2[nt]);
        tk2[nt] = MF(h1, ldB(wfrag, 60 + nt*4 + 1, lane), tk2[nt]);
      }
    }
    // h cols 64..127 (h0/h1 loads precede these stores in program order)
    #pragma unroll
    for (int nt = 4; nt < 8; ++nt){
      float bb = f1b[nt*16 + cl];
      f32x4 c = {bb, bb, bb, bb};
      c = MF(a0, ldB(wfrag, 44 + nt*2 + 0, lane), c);
      c = MF(a1, ldB(wfrag, 44 + nt*2 + 1, lane), c);
      #pragma unroll
      for (int r = 0; r < 4; ++r) c[r] = fmaxf(c[r], 0.f);
      stC(X, 0, nt - 4, c, lane);
    }
    {
      bf16x8 h0 = ldA(X, 0, 0, lane), h1 = ldA(X, 0, 1, lane);
      #pragma unroll
      for (int nt = 0; nt < 4; ++nt){
        tk2[nt] = MF(h0, ldB(wfrag, 60 + nt*4 + 2, lane), tk2[nt]);
        tk2[nt] = MF(h1, ldB(wfrag, 60 + nt*4 + 3, lane), tk2[nt]);
      }
    }
    #pragma unroll
    for (int nt = 0; nt < 4; ++nt)
      #pragma unroll
      for (int r = 0; r < 4; ++r) tk2[nt][r] += res1[nt][r];
    layer_norm16(tk2, ln2g, ln2b, lane);
    #pragma unroll
    for (int nt = 0; nt < 4; ++nt) stC(Q, 0, nt, tk2[nt], lane);
  }

  // ======== Phase G: output MLP + gate + final residual ========
  {
    bf16x8 a0 = ldA(Q, 0, 0, lane), a1 = ldA(Q, 0, 1, lane);
    #pragma unroll
    for (int nt = 0; nt < 4; ++nt){
      float bb = o1b[nt*16 + cl];
      f32x4 c = {bb, bb, bb, bb};
      c = MF(a0, ldB(wfrag, 76 + nt*2 + 0, lane), c);
      c = MF(a1, ldB(wfrag, 76 + nt*2 + 1, lane), c);
      #pragma unroll
      for (int r = 0; r < 4; ++r) c[r] = fmaxf(c[r], 0.f);
      stC(X, 0, nt, c, lane);
    }
    bf16x8 b0 = ldA(X, 0, 0, lane), b1 = ldA(X, 0, 1, lane);
    #pragma unroll
    for (int nt = 0; nt < 4; ++nt){
      float bb = o2b[nt*16 + cl];
      f32x4 c = {bb, bb, bb, bb};
      c = MF(b0, ldB(wfrag, 84 + nt*2 + 0, lane), c);
      c = MF(b1, ldB(wfrag, 84 + nt*2 + 1, lane), c);
      #pragma unroll
      for (int r = 0; r < 4; ++r){
        int row = r0 + r;
        unsigned int fw2 = (unsigned int)__shfl((int)myfw, row*4);
        float keep = (fw2 & 2u) ? 1.f : 0.f;   // history_present gate
        size_t idx = (size_t)(v0 + row)*64 + nt*16 + cl;
        out[idx] = vf[idx] + keep * c[r];
      }
    }
  }
}

extern "C" void kernel_launch(void* const* d_in, const int* in_sizes, int n_in,
                              void* d_out, int out_size, void* d_ws, size_t ws_size,
                              hipStream_t stream)
{
  (void)n_in; (void)out_size; (void)ws_size;
  const float* vf    = (const float*)d_in[0];
  const float* vox   = (const float*)d_in[1];
  const float* pp_w1 = (const float*)d_in[2];
  const float* pp_b1 = (const float*)d_in[3];
  const float* pp_w2 = (const float*)d_in[4];
  const float* pp_b2 = (const float*)d_in[5];
  const float* ipw   = (const float*)d_in[6];
  const float* ipb   = (const float*)d_in[7];
  const float* outw  = (const float*)d_in[8];
  const float* outb  = (const float*)d_in[9];
  const float* ln1g  = (const float*)d_in[10];
  const float* ln1b  = (const float*)d_in[11];
  const float* f1w   = (const float*)d_in[12];
  const float* f1b   = (const float*)d_in[13];
  const float* f2w   = (const float*)d_in[14];
  const float* f2b   = (const float*)d_in[15];
  const float* ln2g  = (const float*)d_in[16];
  const float* ln2b  = (const float*)d_in[17];
  const float* o1w   = (const float*)d_in[18];
  const float* o1b   = (const float*)d_in[19];
  const float* o2w   = (const float*)d_in[20];
  const float* o2b   = (const float*)d_in[21];
  const int*   npts  = (const int*)d_in[22];
  unsigned short* wfrag = (unsigned short*)d_ws;   // 92*512*2 = 94208 B
  float* out = (float*)d_out;

  const int nvox = in_sizes[0] / 64;       // 100000
  const int ngrp = nvox / 16;              // 6250 wave-groups
  const int nblk = (ngrp + 1) / 2;         // 3125 blocks x 2 waves
  tva_pack_weights<<<92, 64, 0, stream>>>(pp_w1, pp_w2, ipw, outw, f1w, f2w, o1w, o2w, wfrag);
  tva_main<<<nblk, 128, 0, stream>>>(vf, vox, npts, pp_b1, pp_b2, ipb, outb,
                                     ln1g, ln1b, f1b, f2b, ln2g, ln2b, o1b, o2b,
                                     wfrag, out, nvox);
}